// Round 6
// baseline (43.079 us; speedup 1.0000x reference)
//
#include <hip/hip_runtime.h>
#include <math.h>

// ---- compile-time problem constants (from setup_inputs) ----
#define B_SZ 2
#define HI 48
#define WI 48
#define NG (HI*WI)          // 2304 gaussians per image
#define NT (B_SZ*NG)        // 4608 total gaussians
#define FD 65               // feat dim (64 conv + factor)
#define HIDN 256
#define HT 96
#define WT 96
#define PT (HT*WT)          // 9216 pixels per image
#define FACTOR 2.0f         // max(96/48, 96/48)
#define OFF_SCALE 0.125f    // 3 * (2*factor / max(Ht,Wt))
#define A_MIN (1.0f/255.0f)
#define A_MAX 0.99f
#define LN255 5.54126354516f   // ln(255): w >= 1/255 <=> sigma <= LN255

#define GPB 8               // gaussians per block in param kernel (8 | 48 -> same row)
#define TS 16               // render tile size (16x16 px, 256 threads)

// ws layout: ga[NT] float4 (px,py,conA,conB) | gb[NT] float4 (conC,r,g,b)
//            | gt[NT] float4 (px,py,rx,ry)

// Layer-2 for one MLP, executed by one wave (m == t>>6, wave-uniform branch).
// Each lane holds acc[4][GPB] = relu(layer1) for h = h0..h0+3, all 8 gaussians.
// outv[gi][OBASE+j] = sum over 256 h = butterfly-allreduce over 64 lanes.
#define L2_BRANCH(W2P, B2P, OD, OBASE)                                        \
  {                                                                           \
    float wv[4*OD];                                                           \
    _Pragma("unroll")                                                         \
    for (int q = 0; q < OD; ++q)                                              \
      *(float4*)&wv[q*4] = *(const float4*)&W2P[h0*OD + q*4];                 \
    float b2v[OD];                                                            \
    _Pragma("unroll")                                                         \
    for (int j = 0; j < OD; ++j) b2v[j] = B2P[j];                             \
    _Pragma("unroll")                                                         \
    for (int j = 0; j < OD; ++j) {                                            \
      _Pragma("unroll")                                                       \
      for (int gi = 0; gi < GPB; ++gi) {                                      \
        float s = acc[0][gi]*wv[0*OD+j] + acc[1][gi]*wv[1*OD+j]               \
                + acc[2][gi]*wv[2*OD+j] + acc[3][gi]*wv[3*OD+j];              \
        s += __shfl_xor(s, 1);  s += __shfl_xor(s, 2);  s += __shfl_xor(s, 4);\
        s += __shfl_xor(s, 8);  s += __shfl_xor(s, 16); s += __shfl_xor(s, 32);\
        if ((t & 63) == 0) outv[gi][OBASE + j] = s + b2v[j];                  \
      }                                                                       \
    }                                                                         \
  }

__global__ __launch_bounds__(256, 4) void param_kernel(
    const float* __restrict__ inp, const float* __restrict__ enc_w, const float* __restrict__ enc_b,
    const float* __restrict__ ow1, const float* __restrict__ ob1, const float* __restrict__ ow2, const float* __restrict__ ob2,
    const float* __restrict__ sw1, const float* __restrict__ sb1, const float* __restrict__ sw2, const float* __restrict__ sb2,
    const float* __restrict__ rw1, const float* __restrict__ rb1, const float* __restrict__ rw2, const float* __restrict__ rb2,
    const float* __restrict__ cw1, const float* __restrict__ cb1, const float* __restrict__ cw2, const float* __restrict__ cb2,
    float4* __restrict__ ga, float4* __restrict__ gb, float4* __restrict__ gt)
{
    __shared__ float sinp[3][3][12];                 // input patch: 3ch x 3 rows x 10 cols (pad 12)
    __shared__ float swt[64*27];                     // conv weights
    __shared__ __align__(16) float feat[GPB][68];    // conv output, float4-readable
    __shared__ float outv[GPB][8];

    const int t  = threadIdx.x;
    const int n0 = blockIdx.x * GPB;
    const int b  = n0 / NG;
    const int pix0 = n0 % NG;
    const int y  = pix0 / WI;
    const int x0 = pix0 % WI;     // block's 8 pixels: (y, x0..x0+7), same row

    // ---- stage conv weights + input patch to LDS ----
    for (int i = t; i < 64*27; i += 256) swt[i] = enc_w[i];
    if (t < 90) {
        int c = t / 30, r = (t / 10) % 3, cc = t % 10;
        int yy = y + r - 1;
        int xx = x0 + cc - 1;
        float v = 0.f;
        if (yy >= 0 && yy < HI && xx >= 0 && xx < WI)
            v = inp[((b*3 + c)*HI + yy)*WI + xx];
        sinp[c][r][cc] = v;
    }
    __syncthreads();

    // ---- conv 3x3 SAME (64 out ch) x 8 gaussians: 512 tasks over 256 threads ----
    for (int rep = 0; rep < 2; ++rep) {
        int idx = rep * 256 + t;
        int gi = idx >> 6, o = idx & 63;
        float acc = enc_b[o];
        #pragma unroll
        for (int c = 0; c < 3; ++c)
            #pragma unroll
            for (int ky = 0; ky < 3; ++ky)
                #pragma unroll
                for (int kx = 0; kx < 3; ++kx)
                    acc += swt[o*27 + c*9 + ky*3 + kx] * sinp[c][ky][gi + kx];
        feat[gi][o] = acc;
    }
    __syncthreads();

    // ---- layer 1: thread = (mlp m, h-quad); 4 h x 8 gi register tile ----
    const int m  = t >> 6;          // wave-uniform
    const int h0 = (t & 63) * 4;
    float acc[4][GPB];
    {
        const float* __restrict__ w1 = (m == 0) ? ow1 : (m == 1) ? sw1 : (m == 2) ? rw1 : cw1;
        const float* __restrict__ b1 = (m == 0) ? ob1 : (m == 1) ? sb1 : (m == 2) ? rb1 : cb1;
        #pragma unroll
        for (int hh = 0; hh < 4; ++hh)
            #pragma unroll
            for (int gi = 0; gi < GPB; ++gi) acc[hh][gi] = 0.f;

        #pragma unroll 4
        for (int it = 0; it < 16; ++it) {           // k = it*4 .. it*4+3
            float4 w0 = *(const float4*)&w1[(it*4 + 0)*HIDN + h0];
            float4 w1v = *(const float4*)&w1[(it*4 + 1)*HIDN + h0];
            float4 w2v = *(const float4*)&w1[(it*4 + 2)*HIDN + h0];
            float4 w3v = *(const float4*)&w1[(it*4 + 3)*HIDN + h0];
            #pragma unroll
            for (int gi = 0; gi < GPB; ++gi) {
                float4 f = *(const float4*)&feat[gi][it*4];
                acc[0][gi] += f.x*w0.x + f.y*w1v.x + f.z*w2v.x + f.w*w3v.x;
                acc[1][gi] += f.x*w0.y + f.y*w1v.y + f.z*w2v.y + f.w*w3v.y;
                acc[2][gi] += f.x*w0.z + f.y*w1v.z + f.z*w2v.z + f.w*w3v.z;
                acc[3][gi] += f.x*w0.w + f.y*w1v.w + f.z*w2v.w + f.w*w3v.w;
            }
        }
        // effective bias: b1 + FACTOR * w1[k=64 row]  (feat[64] == FACTOR const)
        float4 bb = *(const float4*)&b1[h0];
        float4 wl = *(const float4*)&w1[64*HIDN + h0];
        bb.x += FACTOR * wl.x; bb.y += FACTOR * wl.y;
        bb.z += FACTOR * wl.z; bb.w += FACTOR * wl.w;
        #pragma unroll
        for (int gi = 0; gi < GPB; ++gi) {
            acc[0][gi] = fmaxf(acc[0][gi] + bb.x, 0.f);
            acc[1][gi] = fmaxf(acc[1][gi] + bb.y, 0.f);
            acc[2][gi] = fmaxf(acc[2][gi] + bb.z, 0.f);
            acc[3][gi] = fmaxf(acc[3][gi] + bb.w, 0.f);
        }
    }

    // ---- layer 2 fused in registers + wave butterfly reduce (no LDS hid) ----
    if (m == 0)      L2_BRANCH(ow2, ob2, 2, 0)
    else if (m == 1) L2_BRANCH(sw2, sb2, 2, 2)
    else if (m == 2) L2_BRANCH(rw2, rb2, 1, 4)
    else             L2_BRANCH(cw2, cb2, 3, 5)
    __syncthreads();

    // ---- activations + projection + conic + cull radii, one thread per gaussian ----
    if (t < GPB) {
        int gi = t, n = n0 + gi;
        int x = x0 + gi;
        float cy = -1.f + (2.f*y + 1.f) / (float)HI;
        float cx = -1.f + (2.f*x + 1.f) / (float)WI;
        float xyy = cy + tanhf(outv[gi][0]) * OFF_SCALE;
        float xyx = cx + tanhf(outv[gi][1]) * OFF_SCALE;
        float pxp = (xyx + 1.f) * 0.5f * (float)WT - 0.5f;
        float pyp = (xyy + 1.f) * 0.5f * (float)HT - 0.5f;
        float t2 = outv[gi][2], t3 = outv[gi][3];
        float s0 = (t2 > 0.f ? t2 : expf(t2) - 1.f) + 1.5f;
        float s1 = (t3 > 0.f ? t3 : expf(t3) - 1.f) + 1.5f;
        float rot = tanhf(outv[gi][4]) * 3.14159265358979323846f;
        float cr = cosf(rot), sr = sinf(rot);
        float sx2 = s0*s0, sy2 = s1*s1;
        float cov_a = cr*cr*sx2 + sr*sr*sy2;
        float cov_b = cr*sr*(sx2 - sy2);
        float cov_c = sr*sr*sx2 + cr*cr*sy2;
        float det = cov_a*cov_c - cov_b*cov_b;
        float conA = cov_c / det, conB = -cov_b / det, conC = cov_a / det;
        float c0 = 1.f/(1.f + expf(-outv[gi][5]));
        float c1 = 1.f/(1.f + expf(-outv[gi][6]));
        float c2 = 1.f/(1.f + expf(-outv[gi][7]));
        // ellipse {sigma <= ln255} bbox half-extents: sqrt(2*ln255*(cov)_ii)
        float rx = sqrtf(2.f * LN255 * cov_a);
        float ry = sqrtf(2.f * LN255 * cov_c);
        ga[n] = make_float4(pxp, pyp, conA, conB);
        gb[n] = make_float4(conC, c0, c1, c2);
        gt[n] = make_float4(pxp, pyp, rx, ry);
    }
}

__global__ __launch_bounds__(256) void render_kernel(
    const float4* __restrict__ ga, const float4* __restrict__ gb,
    const float4* __restrict__ gt, float* __restrict__ out)
{
    __shared__ unsigned short sidx[NG];
    __shared__ int ns;
    __shared__ __align__(16) float4 lp0[256];
    __shared__ __align__(16) float4 lp1[256];

    const int t    = threadIdx.x;
    const int b    = blockIdx.y;
    const int tile = blockIdx.x;                  // 0..35
    const int tx   = (tile % (WT/TS)) * TS;
    const int ty   = (tile / (WT/TS)) * TS;
    const float cx = tx + (TS-1)*0.5f;
    const float cy = ty + (TS-1)*0.5f;
    const float hw = (TS-1)*0.5f;

    if (t == 0) ns = 0;
    __syncthreads();

    // ---- phase 1: conservative bbox test, compact survivor indices ----
    #pragma unroll
    for (int i = 0; i < NG/256; ++i) {            // 9 gaussians per thread
        int n = i*256 + t;
        float4 v = gt[b*NG + n];                  // px, py, rx, ry
        if (fabsf(v.x - cx) <= v.z + hw && fabsf(v.y - cy) <= v.w + hw) {
            int slot = atomicAdd(&ns, 1);
            sidx[slot] = (unsigned short)n;
        }
    }
    __syncthreads();
    const int total = ns;

    const float gxf = (float)(tx + (t & (TS-1)));
    const float gyf = (float)(ty + (t / TS));
    float ra = 0.f, gg = 0.f, ba = 0.f, aa = 0.f;

    // ---- phase 2: chunks of 256 survivors staged to LDS, exact evaluation ----
    for (int base = 0; base < total; base += 256) {
        int cn = min(256, total - base);
        __syncthreads();
        if (t < cn) {
            int n = b*NG + sidx[base + t];
            lp0[t] = ga[n];                       // px, py, conA, conB
            lp1[t] = gb[n];                       // conC, r, g, b
        }
        __syncthreads();
        #pragma unroll 4
        for (int j = 0; j < cn; ++j) {
            float4 c0 = lp0[j];
            float4 c1 = lp1[j];
            float dx = gxf - c0.x, dy = gyf - c0.y;
            float sigma = 0.5f*(c0.z*dx*dx + c1.x*dy*dy) + c0.w*(dx*dy);
            float w = __expf(-sigma);
            float alpha = (sigma >= 0.f && w >= A_MIN) ? fminf(w, A_MAX) : 0.f;
            ra += alpha * c1.y;
            gg += alpha * c1.z;
            ba += alpha * c1.w;
            aa += alpha;
        }
    }

    float T = fminf(fmaxf(1.f - aa, 0.f), 1.f);
    int o = (b*PT + (ty + t/TS)*WT + tx + (t & (TS-1))) * 3;
    out[o + 0] = ra + T;
    out[o + 1] = gg + T;
    out[o + 2] = ba + T;
}

extern "C" void kernel_launch(void* const* d_in, const int* in_sizes, int n_in,
                              void* d_out, int out_size, void* d_ws, size_t ws_size,
                              hipStream_t stream)
{
    const float* inp   = (const float*)d_in[0];
    const float* enc_w = (const float*)d_in[1];
    const float* enc_b = (const float*)d_in[2];
    const float* ow1 = (const float*)d_in[3];
    const float* ob1 = (const float*)d_in[4];
    const float* ow2 = (const float*)d_in[5];
    const float* ob2 = (const float*)d_in[6];
    const float* sw1 = (const float*)d_in[7];
    const float* sb1 = (const float*)d_in[8];
    const float* sw2 = (const float*)d_in[9];
    const float* sb2 = (const float*)d_in[10];
    const float* rw1 = (const float*)d_in[11];
    const float* rb1 = (const float*)d_in[12];
    const float* rw2 = (const float*)d_in[13];
    const float* rb2 = (const float*)d_in[14];
    const float* cw1 = (const float*)d_in[15];
    const float* cb1 = (const float*)d_in[16];
    const float* cw2 = (const float*)d_in[17];
    const float* cb2 = (const float*)d_in[18];

    float4* ga = (float4*)d_ws;            // NT float4
    float4* gb = ga + NT;                  // NT float4
    float4* gt = gb + NT;                  // NT float4

    param_kernel<<<NT/GPB, 256, 0, stream>>>(inp, enc_w, enc_b,
                                             ow1, ob1, ow2, ob2,
                                             sw1, sb1, sw2, sb2,
                                             rw1, rb1, rw2, rb2,
                                             cw1, cb1, cw2, cb2,
                                             ga, gb, gt);
    render_kernel<<<dim3((WT/TS)*(HT/TS), B_SZ), 256, 0, stream>>>(ga, gb, gt, (float*)d_out);
}